// Round 4
// baseline (74.070 us; speedup 1.0000x reference)
//
#include <hip/hip_runtime.h>

// 16-bit ripple-borrow subtractor on {0,1} float bits.
// Per row: pack bits LSB-first into uint16; diff = (a-b) & 0xFFFF, borrow = a<b.
// Lane-per-float4 layout: thread g owns bits [4q..4q+3] of row g>>2, so every
// global load/store is stride-1 across lanes (fully coalesced). The 16-bit
// words are assembled within each 4-lane group via 2x shfl_xor.
// R4 experiment: plain (cacheable) stores instead of nontemporal — let the
// 256 MiB Infinity Cache absorb the replay-to-replay output overwrites so
// WRITE_SIZE (HBM) drops below the logical 140 MB.

typedef float vfloat4 __attribute__((ext_vector_type(4)));

__global__ __launch_bounds__(256) void sub16_kernel(
    const vfloat4* __restrict__ A4,
    const vfloat4* __restrict__ B4,
    vfloat4* __restrict__ D4,
    float* __restrict__ borrow,
    int nquads)
{
    int g = blockIdx.x * blockDim.x + threadIdx.x;  // quad index
    if (g >= nquads) return;

    int q   = g & 3;   // quad within row
    int row = g >> 2;

    vfloat4 av = A4[g];
    vfloat4 bv = B4[g];

    unsigned na = (unsigned)(av.x != 0.0f)
                | ((unsigned)(av.y != 0.0f) << 1)
                | ((unsigned)(av.z != 0.0f) << 2)
                | ((unsigned)(av.w != 0.0f) << 3);
    unsigned nb = (unsigned)(bv.x != 0.0f)
                | ((unsigned)(bv.y != 0.0f) << 1)
                | ((unsigned)(bv.z != 0.0f) << 2)
                | ((unsigned)(bv.w != 0.0f) << 3);

    int sh = q << 2;
    unsigned packed = (na << sh) | (nb << (16 + sh));

    // OR-combine across the 4-lane group (lanes differ only in q)
    packed |= __shfl_xor(packed, 1);
    packed |= __shfl_xor(packed, 2);

    unsigned a = packed & 0xFFFFu;
    unsigned b = packed >> 16;
    unsigned d = (a - b) & 0xFFFFu;

    vfloat4 v;
    v.x = (float)((d >> (sh + 0)) & 1u);
    v.y = (float)((d >> (sh + 1)) & 1u);
    v.z = (float)((d >> (sh + 2)) & 1u);
    v.w = (float)((d >> (sh + 3)) & 1u);
    D4[g] = v;

    if (q == 0) {
        borrow[row] = (float)(a < b);
    }
}

extern "C" void kernel_launch(void* const* d_in, const int* in_sizes, int n_in,
                              void* d_out, int out_size, void* d_ws, size_t ws_size,
                              hipStream_t stream) {
    const vfloat4* A4 = (const vfloat4*)d_in[0];
    const vfloat4* B4 = (const vfloat4*)d_in[1];
    float* out = (float*)d_out;

    int batch  = in_sizes[0] / 16;
    int nquads = batch * 4;

    vfloat4* D4   = (vfloat4*)out;              // [batch, 16] floats
    float* borrow = out + (size_t)batch * 16;   // [batch, 1]

    int block = 256;
    int grid  = (nquads + block - 1) / block;
    sub16_kernel<<<grid, block, 0, stream>>>(A4, B4, D4, borrow, nquads);
}

// Round 5
// 62.484 us; speedup vs baseline: 1.1854x; 1.1854x over previous
//
#include <hip/hip_runtime.h>

// 16-bit ripple-borrow subtractor on {0,1} float bits.
// Per row: pack bits LSB-first into uint16; diff = (a-b) & 0xFFFF, borrow = a<b.
// Lane-per-float4 layout (R3): thread-lane g owns bits [4q..4q+3] of row g>>2;
// all global accesses stride-1 across lanes. 16-bit words assembled in the
// 4-lane group via 2x shfl_xor. Nontemporal stores (R4 showed cacheable
// stores regress: WRITE_SIZE unchanged, dur +19%).
// R5: 2x ILP — each thread handles two quads (g and g+half) so 4 independent
// loads are in flight before the dependent pack/shuffle/store chain.

typedef float vfloat4 __attribute__((ext_vector_type(4)));

__global__ __launch_bounds__(256) void sub16_kernel(
    const vfloat4* __restrict__ A4,
    const vfloat4* __restrict__ B4,
    vfloat4* __restrict__ D4,
    float* __restrict__ borrow,
    int half)   // = nquads/2
{
    int t = blockIdx.x * blockDim.x + threadIdx.x;
    if (t >= half) return;

    int g0 = t;
    int g1 = t + half;

    // issue all 4 loads up front
    vfloat4 av0 = A4[g0];
    vfloat4 bv0 = B4[g0];
    vfloat4 av1 = A4[g1];
    vfloat4 bv1 = B4[g1];

    int q   = t & 3;
    int sh  = q << 2;

#define PACK4(v) ( (unsigned)((v).x != 0.0f)        \
                 | ((unsigned)((v).y != 0.0f) << 1) \
                 | ((unsigned)((v).z != 0.0f) << 2) \
                 | ((unsigned)((v).w != 0.0f) << 3) )

    unsigned p0 = (PACK4(av0) << sh) | (PACK4(bv0) << (16 + sh));
    unsigned p1 = (PACK4(av1) << sh) | (PACK4(bv1) << (16 + sh));
#undef PACK4

    // OR-combine across the 4-lane group (lanes differ only in q)
    p0 |= __shfl_xor(p0, 1);
    p0 |= __shfl_xor(p0, 2);
    p1 |= __shfl_xor(p1, 1);
    p1 |= __shfl_xor(p1, 2);

    unsigned a0 = p0 & 0xFFFFu, b0 = p0 >> 16;
    unsigned a1 = p1 & 0xFFFFu, b1 = p1 >> 16;
    unsigned d0 = (a0 - b0) & 0xFFFFu;
    unsigned d1 = (a1 - b1) & 0xFFFFu;

    vfloat4 v0, v1;
    v0.x = (float)((d0 >> (sh + 0)) & 1u);
    v0.y = (float)((d0 >> (sh + 1)) & 1u);
    v0.z = (float)((d0 >> (sh + 2)) & 1u);
    v0.w = (float)((d0 >> (sh + 3)) & 1u);
    v1.x = (float)((d1 >> (sh + 0)) & 1u);
    v1.y = (float)((d1 >> (sh + 1)) & 1u);
    v1.z = (float)((d1 >> (sh + 2)) & 1u);
    v1.w = (float)((d1 >> (sh + 3)) & 1u);
    __builtin_nontemporal_store(v0, &D4[g0]);
    __builtin_nontemporal_store(v1, &D4[g1]);

    if (q == 0) {
        __builtin_nontemporal_store((float)(a0 < b0), &borrow[g0 >> 2]);
        __builtin_nontemporal_store((float)(a1 < b1), &borrow[g1 >> 2]);
    }
}

extern "C" void kernel_launch(void* const* d_in, const int* in_sizes, int n_in,
                              void* d_out, int out_size, void* d_ws, size_t ws_size,
                              hipStream_t stream) {
    const vfloat4* A4 = (const vfloat4*)d_in[0];
    const vfloat4* B4 = (const vfloat4*)d_in[1];
    float* out = (float*)d_out;

    int batch  = in_sizes[0] / 16;
    int nquads = batch * 4;
    int half   = nquads / 2;

    vfloat4* D4   = (vfloat4*)out;              // [batch, 16] floats
    float* borrow = out + (size_t)batch * 16;   // [batch, 1]

    int block = 256;
    int grid  = (half + block - 1) / block;
    sub16_kernel<<<grid, block, 0, stream>>>(A4, B4, D4, borrow, half);
}